// Round 2
// 336.620 us; speedup vs baseline: 1.0986x; 1.0986x over previous
//
#include <hip/hip_runtime.h>
#include <math.h>

#define N_NODES 40000
#define N_EDGES 640000
#define IN_CH 128
#define HID_CH 256
#define EDGE_DIM 64
#define N_SAMP 2048
#define NSEL (1 + 2 * N_SAMP) /* 4097 selected rows */
#define MAXU 4097             /* max unique selected nodes */
#define HBUCKETS 5120         /* hist padded */
#define CAP 64                /* max edges per slot bucket; P(deg>=64) < 1e-18 at lambda=16 */
#define MROWS 8               /* rows per mlp block */

// ---------------------------------------------------------------------------
// Init: slot=-1, hist=0, counters=0. agg_c needs no zeroing (edge kernel
// fully overwrites every slot row with a plain store).
// ---------------------------------------------------------------------------
__global__ __launch_bounds__(256) void init_kernel(
    int* __restrict__ slot, int* __restrict__ counters, int* __restrict__ hist)
{
    const int i = blockIdx.x * 256 + threadIdx.x; // grid 160 -> 40960 threads
    if (i < 40960) slot[i] = -1;
    if (i < HBUCKETS) hist[i] = 0;
    if (i < 32) counters[i] = 0;
}

// ---------------------------------------------------------------------------
// Assign compact slots to selected nodes (dedup via atomicCAS).
// ---------------------------------------------------------------------------
__global__ __launch_bounds__(256) void flag_kernel(
    const int* __restrict__ pos, const int* __restrict__ neg,
    int* __restrict__ slot, int* __restrict__ counters)
{
    int r = blockIdx.x * 256 + threadIdx.x;
    if (r >= NSEL) return;
    int node = (r == 0) ? 0 : (r <= N_SAMP ? pos[r - 1] : neg[r - 1 - N_SAMP]);
    int old = atomicCAS(&slot[node], -1, -2);
    if (old == -1) slot[node] = atomicAdd(&counters[1], 1);
}

// ---------------------------------------------------------------------------
// Direct per-slot bucket scatter (replaces compact+scan+scatter).
// bucket[sl*CAP + p] = {attr_row e, src}.  hist[sl] = count.
// ---------------------------------------------------------------------------
__global__ __launch_bounds__(256) void bucket_kernel(
    const int* __restrict__ ei, const int* __restrict__ slot,
    int* __restrict__ hist, int2* __restrict__ bucket)
{
    const int e = blockIdx.x * 256 + threadIdx.x; // grid 2500 exact
    const int d = ei[N_EDGES + e];
    const int sl = slot[d];
    if (sl >= 0) {
        int p = atomicAdd(&hist[sl], 1);
        if (p < CAP) bucket[(size_t)sl * CAP + p] = make_int2(e, ei[e]);
    }
}

// ---------------------------------------------------------------------------
// Edge GEMM, one wave per slot: register accumulation over the slot's bucket,
// ZERO atomics, one plain 512B store per slot. Chunks of 8 edges; trip count
// is block-uniform (max over the block's 4 slots) so __syncthreads is safe.
// ---------------------------------------------------------------------------
__global__ __launch_bounds__(256) void edge_kernel(
    const float* __restrict__ x, const float* __restrict__ edge_attr,
    const float* __restrict__ We, const float* __restrict__ be,
    const int* __restrict__ hist, const int2* __restrict__ bucket,
    float* __restrict__ agg_c)
{
    __shared__ float sWe[EDGE_DIM * IN_CH];   // 32 KB
    __shared__ float sA[4][8][EDGE_DIM];      // 8 KB
    __shared__ int scnt[4];
    const int tid = threadIdx.x, wave = tid >> 6, lane = tid & 63;

    { // stage We once
        const float4* s4 = (const float4*)We;
        float4* d4 = (float4*)sWe;
        for (int i = tid; i < (EDGE_DIM * IN_CH) / 4; i += 256) d4[i] = s4[i];
    }
    const int s = blockIdx.x * 4 + wave;      // slot id, 0..4099 (grid 1025)
    const int cnt = min(hist[s], CAP);        // hist padded to 5120; s>=NU reads 0
    if (lane == 0) scnt[wave] = cnt;
    __syncthreads();                           // covers sWe staging + scnt
    const int cmax = max(max(scnt[0], scnt[1]), max(scnt[2], scnt[3]));

    const float be0 = be[lane], be1 = be[64 + lane];
    // clamp: s in [MAXU,4100) has cnt==0, bk never deref'd; clamp avoids OOB ptr UB
    const int2* bk = bucket + (size_t)min(s, MAXU - 1) * CAP;
    float sum0 = 0.f, sum1 = 0.f;

    for (int c0 = 0; c0 < cmax; c0 += 8) {
        // lanes hold entry c0+(lane&7); __shfl(.,j) broadcasts entry c0+j
        int2 bv = make_int2(0, 0);
        {
            int jj = lane & 7;
            if (c0 + jj < cnt) bv = bk[c0 + jj];
        }
        // stage 8 attr rows (invalid rows zeroed -> contribute 0 to acc)
#pragma unroll
        for (int j = 0; j < 8; ++j) {
            int e = __shfl(bv.x, j);
            float a = 0.f;
            if (c0 + j < cnt) a = edge_attr[(size_t)e * EDGE_DIM + lane];
            sA[wave][j][lane] = a;
        }
        // issue x-row gathers early; consumed after the k-loop (latency hidden)
        float xr0[8], xr1[8];
#pragma unroll
        for (int j = 0; j < 8; ++j) {
            int src = __shfl(bv.y, j);
            bool v = (c0 + j < cnt);
            size_t off = (size_t)src * IN_CH;
            xr0[j] = v ? x[off + lane] : 0.f;
            xr1[j] = v ? x[off + 64 + lane] : 0.f;
        }
        __syncthreads(); // sA writes visible (uniform trip count across block)

        float acc0[8], acc1[8];
#pragma unroll
        for (int j = 0; j < 8; ++j) { acc0[j] = 0.f; acc1[j] = 0.f; }
        for (int k0 = 0; k0 < EDGE_DIM; k0 += 4) {
            float w0[4], w1[4];
#pragma unroll
            for (int kk = 0; kk < 4; ++kk) {
                w0[kk] = sWe[(k0 + kk) * IN_CH + lane];
                w1[kk] = sWe[(k0 + kk) * IN_CH + 64 + lane];
            }
#pragma unroll
            for (int j = 0; j < 8; ++j) {
                float4 a = *(const float4*)&sA[wave][j][k0]; // broadcast b128
                acc0[j] += a.x * w0[0] + a.y * w0[1] + a.z * w0[2] + a.w * w0[3];
                acc1[j] += a.x * w1[0] + a.y * w1[1] + a.z * w1[2] + a.w * w1[3];
            }
        }
#pragma unroll
        for (int j = 0; j < 8; ++j) {
            if (c0 + j < cnt) { // wave-uniform branch
                sum0 += fmaxf(xr0[j] + acc0[j] + be0, 0.f);
                sum1 += fmaxf(xr1[j] + acc1[j] + be1, 0.f);
            }
        }
        __syncthreads(); // protect sA before next chunk's staging
    }
    // agg_c padded to 4100 rows; s <= 4099, so store unconditionally.
    agg_c[(size_t)s * IN_CH + lane] = sum0;
    agg_c[(size_t)s * IN_CH + 64 + lane] = sum1;
}

// ---------------------------------------------------------------------------
// Fused MLP: emb[r] = relu((x[n]+agg_c[slot[n]]) @ W1 + b1) @ W2 + b2
// 8 rows/block (513 blocks -> ~2 blocks/CU for latency hiding).
// ---------------------------------------------------------------------------
__global__ __launch_bounds__(256) void mlp_kernel(
    const float* __restrict__ x, const float* __restrict__ agg_c,
    const int* __restrict__ slot, const int* __restrict__ pos,
    const int* __restrict__ neg, const float* __restrict__ W1,
    const float* __restrict__ b1, const float* __restrict__ W2,
    const float* __restrict__ b2, float* __restrict__ emb)
{
    __shared__ float sin_[MROWS][IN_CH];   // 4 KB
    __shared__ float shid[MROWS][HID_CH];  // 8 KB
    __shared__ int snode[MROWS], sslot[MROWS];
    const int tid = threadIdx.x;
    const int r0 = blockIdx.x * MROWS;
    if (tid < MROWS) {
        int r = r0 + tid;
        int node = 0;
        if (r < NSEL && r > 0) node = (r <= N_SAMP) ? pos[r - 1] : neg[r - 1 - N_SAMP];
        snode[tid] = node;
        sslot[tid] = slot[node]; // node 0 always selected -> slot >= 0
    }
    __syncthreads();
    { // 8 rows x 32 float4 = 256 -> exactly one pass
        int rr = tid >> 5, k4 = tid & 31;
        int n = snode[rr], sl = sslot[rr];
        float4 xa = ((const float4*)(x + (size_t)n * IN_CH))[k4];
        float4 ga = ((const float4*)(agg_c + (size_t)sl * IN_CH))[k4];
        ((float4*)sin_[rr])[k4] =
            make_float4(xa.x + ga.x, xa.y + ga.y, xa.z + ga.z, xa.w + ga.w);
    }
    __syncthreads();

    float acc[MROWS];
#pragma unroll
    for (int rr = 0; rr < MROWS; ++rr) acc[rr] = 0.f;
    for (int k0 = 0; k0 < IN_CH; k0 += 4) {
        float w[4];
#pragma unroll
        for (int kk = 0; kk < 4; ++kk) w[kk] = W1[(k0 + kk) * HID_CH + tid];
#pragma unroll
        for (int rr = 0; rr < MROWS; ++rr) {
            float4 h = *(const float4*)&sin_[rr][k0]; // broadcast b128
            acc[rr] += h.x * w[0] + h.y * w[1] + h.z * w[2] + h.w * w[3];
        }
    }
    float bb1 = b1[tid];
#pragma unroll
    for (int rr = 0; rr < MROWS; ++rr) shid[rr][tid] = fmaxf(acc[rr] + bb1, 0.f);
    __syncthreads();

#pragma unroll
    for (int rr = 0; rr < MROWS; ++rr) acc[rr] = 0.f;
    for (int k0 = 0; k0 < HID_CH; k0 += 4) {
        float w[4];
#pragma unroll
        for (int kk = 0; kk < 4; ++kk) w[kk] = W2[(k0 + kk) * HID_CH + tid];
#pragma unroll
        for (int rr = 0; rr < MROWS; ++rr) {
            float4 h = *(const float4*)&shid[rr][k0]; // broadcast b128
            acc[rr] += h.x * w[0] + h.y * w[1] + h.z * w[2] + h.w * w[3];
        }
    }
    float bb2 = b2[tid];
#pragma unroll
    for (int rr = 0; rr < MROWS; ++rr) {
        int r = r0 + rr;
        if (r < NSEL) emb[(size_t)r * HID_CH + tid] = acc[rr] + bb2;
    }
}

// ---------------------------------------------------------------------------
// Scores: one wave per sample row; cosine vs center (emb row 0).
// ---------------------------------------------------------------------------
__global__ __launch_bounds__(256) void score_kernel(
    const float* __restrict__ emb, float* __restrict__ partial)
{
    const int tid = threadIdx.x;
    const int wave = tid >> 6, lane = tid & 63;
    const int rid = blockIdx.x * 4 + wave; // 0..4095
    const float4 c = ((const float4*)emb)[lane];
    const float4 v = ((const float4*)(emb + (size_t)(rid + 1) * HID_CH))[lane];
    float cc = c.x * c.x + c.y * c.y + c.z * c.z + c.w * c.w;
    float vv = v.x * v.x + v.y * v.y + v.z * v.z + v.w * v.w;
    float cv = c.x * v.x + c.y * v.y + c.z * v.z + c.w * v.w;
#pragma unroll
    for (int off = 32; off; off >>= 1) {
        cc += __shfl_xor(cc, off, 64);
        vv += __shfl_xor(vv, off, 64);
        cv += __shfl_xor(cv, off, 64);
    }
    float score = cv / (fmaxf(sqrtf(cc), 1e-12f) * fmaxf(sqrtf(vv), 1e-12f));
    __shared__ float wsum[4];
    if (lane == 0) wsum[wave] = score;
    __syncthreads();
    if (tid == 0) partial[blockIdx.x] = wsum[0] + wsum[1] + wsum[2] + wsum[3];
}

__global__ __launch_bounds__(64) void loss_kernel(
    const float* __restrict__ emb, const float* __restrict__ thrn,
    const float* __restrict__ partial, float* __restrict__ out)
{
    const int lane = threadIdx.x;
    const float4 c = ((const float4*)emb)[lane];
    const float4 t = ((const float4*)thrn)[lane];
    float cc = c.x * c.x + c.y * c.y + c.z * c.z + c.w * c.w;
    float tt = t.x * t.x + t.y * t.y + t.z * t.z + t.w * t.w;
    float ct = c.x * t.x + c.y * t.y + c.z * t.z + c.w * t.w;
    float ps = 0.f, ns = 0.f;
#pragma unroll
    for (int i = 0; i < 8; ++i) ps += partial[lane + 64 * i];
#pragma unroll
    for (int i = 0; i < 8; ++i) ns += partial[512 + lane + 64 * i];
#pragma unroll
    for (int off = 32; off; off >>= 1) {
        cc += __shfl_xor(cc, off, 64);
        tt += __shfl_xor(tt, off, 64);
        ct += __shfl_xor(ct, off, 64);
        ps += __shfl_xor(ps, off, 64);
        ns += __shfl_xor(ns, off, 64);
    }
    if (lane == 0) {
        float thr = ct / (fmaxf(sqrtf(cc), 1e-12f) * fmaxf(sqrtf(tt), 1e-12f));
        float pm = ps / (float)N_SAMP;
        float nm = ns / (float)N_SAMP;
        float s1 = 1.f / (1.f + expf(-(pm - thr)));
        float s2 = 1.f / (1.f + expf(-(thr - nm)));
        s1 = fmaxf(s1, 1e-12f);
        s2 = fmaxf(s2, 1e-12f);
        out[0] = -(logf(s1) + logf(s2));
    }
}

extern "C" void kernel_launch(void* const* d_in, const int* in_sizes, int n_in,
                              void* d_out, int out_size, void* d_ws, size_t ws_size,
                              hipStream_t stream)
{
    const float* x         = (const float*)d_in[0];
    const int*   ei        = (const int*)d_in[1];
    const float* edge_attr = (const float*)d_in[2];
    const int*   pos       = (const int*)d_in[3];
    const int*   neg       = (const int*)d_in[4];
    const float* We        = (const float*)d_in[5];
    const float* be        = (const float*)d_in[6];
    const float* W1        = (const float*)d_in[7];
    const float* b1        = (const float*)d_in[8];
    const float* W2        = (const float*)d_in[9];
    const float* b2        = (const float*)d_in[10];
    const float* thrn      = (const float*)d_in[11];
    float* out = (float*)d_out;

    int* slot     = (int*)d_ws;                         // 40960 ints
    int* counters = slot + 40960;                       // 32
    int* hist     = counters + 32;                      // 5120
    int2* bucket  = (int2*)(hist + HBUCKETS);           // 4097*64 int2 (16B-aligned base)
    float* agg_c  = (float*)(bucket + (size_t)MAXU * CAP); // 4100*128 floats
    float* emb    = agg_c + 4100 * IN_CH;               // 4097*256 floats
    float* partial= emb + (size_t)NSEL * HID_CH;        // 1024 floats

    init_kernel<<<160, 256, 0, stream>>>(slot, counters, hist);
    flag_kernel<<<(NSEL + 255) / 256, 256, 0, stream>>>(pos, neg, slot, counters);
    bucket_kernel<<<N_EDGES / 256, 256, 0, stream>>>(ei, slot, hist, bucket);
    edge_kernel<<<1025, 256, 0, stream>>>(x, edge_attr, We, be, hist, bucket, agg_c);
    mlp_kernel<<<(NSEL + MROWS - 1) / MROWS, 256, 0, stream>>>(x, agg_c, slot, pos, neg,
                                                               W1, b1, W2, b2, emb);
    score_kernel<<<1024, 256, 0, stream>>>(emb, partial);
    loss_kernel<<<1, 64, 0, stream>>>(emb, thrn, partial, out);
}